// Round 3
// baseline (620.008 us; speedup 1.0000x reference)
//
#include <hip/hip_runtime.h>
#include <hip/hip_cooperative_groups.h>

namespace cg = cooperative_groups;

// Sparse 2-hop GCN slice, fully fused into ONE cooperative kernel.
// Output depends only on h2[tgt], tgt = argmax(mut_mask) (one-hot).
// Phases (grid.sync between): init+argmax-partials | argmax-reduce |
// convert+passA | passB | passC(deg) | h1 matvecs | h2 matvecs | MLP head.

#define SCAP   512      // cap on |S1|; expected ~17
#define L1CAP  512      // cap on edges into tgt; expected ~17
#define L2CAP  16384    // cap on edges into S1; expected ~300
#define HID    256
#define INDIM  128
#define NBLK   512
#define NTHR   256

struct Params {
  int* cnt;                 // [0]=cntL1 [1]=cntS1 [2]=cntL2 [3]=is64 [4]=tgt
  float* deg;               // [N] lazily initialized
  int* slot;                // [N] -1 unknown, >=0 S1 slot, -3 deg-needed
  int* s1;                  // [SCAP]
  int* l1r; float* l1w;     // edges into tgt
  int* l2r; int* l2s; float* l2w; // edges into S1
  float* h1; float* h2;     // accumulators
  int* wscol;               // [E] col as int32
  unsigned long long* blkKey; // [NBLK] argmax partials
  const float* x; const int* ei; const float* ew; const float* mask;
  const int* wtI; const int* mutI;
  const float* W1; const float* b1; const float* W2; const float* b2;
  const float* aa; const float* pemb;
  const float* Wh1; const float* bh1; const float* Wh2; const float* bh2;
  const float* Wh3; const float* bh3;
  float* out;
  int N; int E;
};

__global__ void __launch_bounds__(NTHR, 2) kfused(Params p) {
  cg::grid_group grid = cg::this_grid();
  __shared__ unsigned long long shk[NTHR];
  __shared__ float shf[1120];   // head: feat 480 | f1 512 | f2 128 (reused by h1/h2)
  const int tid = threadIdx.x;
  const int g = blockIdx.x * NTHR + tid;
  const int gs = gridDim.x * NTHR;
  const int N = p.N, E = p.E;
  const long long* ell = (const long long*)p.ei;

  // ---------- P0: init + is64 detect + per-block argmax partials ----------
  for (int j = g; j < SCAP * HID; j += gs) p.h1[j] = 0.f;
  for (int j = g; j < N; j += gs) p.slot[j] = -1;
  if (g < HID) p.h2[g] = 0.f;
  if (g < 8 && g != 3) p.cnt[g] = 0;
  if (g == 0) {
    int is64 = 1;
    long step = E / 20; if (step < 1) step = 1;
    for (int j = 1; j <= 16; ++j) {
      long idx = (long)j * step; if (idx >= E) break;
      if (p.ei[2 * idx + 1] != 0) { is64 = 0; break; }   // ids < 2^31 -> hi word 0
    }
    p.cnt[3] = is64;
  }
  {
    unsigned long long best = 0xFFFFFFFFull;   // (value 0.0, idx 0) sentinel
    for (int j = g; j < N; j += gs) {
      float m = p.mask[j];
      if (m > 0.f) {
        unsigned long long kk = ((unsigned long long)__float_as_uint(m) << 32)
                              | (unsigned long long)(0xFFFFFFFFu - (unsigned)j);
        if (kk > best) best = kk;
      }
    }
    shk[tid] = best;
    __syncthreads();
    for (int s = NTHR / 2; s > 0; s >>= 1) {
      if (tid < s && shk[tid + s] > shk[tid]) shk[tid] = shk[tid + s];
      __syncthreads();
    }
    if (tid == 0) p.blkKey[blockIdx.x] = shk[0];
  }
  grid.sync();

  // ---------- P1: block 0 reduces argmax partials -> tgt ----------
  if (blockIdx.x == 0) {
    unsigned long long best = 0xFFFFFFFFull;
    for (int j = tid; j < NBLK; j += NTHR) {
      unsigned long long v = p.blkKey[j];
      if (v > best) best = v;
    }
    shk[tid] = best;
    __syncthreads();
    for (int s = NTHR / 2; s > 0; s >>= 1) {
      if (tid < s && shk[tid + s] > shk[tid]) shk[tid] = shk[tid + s];
      __syncthreads();
    }
    if (tid == 0) p.cnt[4] = (int)(0xFFFFFFFFu - (unsigned)(shk[0] & 0xFFFFFFFFull));
  }
  grid.sync();

  const int tgt = p.cnt[4];
  const bool is64 = p.cnt[3] != 0;

  // ---------- P2: convert col -> int32 AND passA (edges into tgt, build S1) ----------
  for (long e = g; e < E; e += gs) {
    int c = is64 ? (int)ell[(long)E + e] : p.ei[(long)E + e];
    p.wscol[e] = c;
    if (c == tgt) {
      int r = is64 ? (int)ell[e] : p.ei[e];
      int i1 = atomicAdd(&p.cnt[0], 1);
      if (i1 < L1CAP) { p.l1r[i1] = r; p.l1w[i1] = p.ew[e]; }
      int old = atomicCAS(&p.slot[r], -1, -2);
      if (old == -1) {
        p.deg[r] = 1.0f;
        int idx = atomicAdd(&p.cnt[1], 1);
        if (idx < SCAP) { p.s1[idx] = r; p.slot[r] = idx; }
        else            { p.slot[r] = -3; }
      }
    }
  }
  if (g == 0) {  // tgt's self loop (weight 1.0)
    int i1 = atomicAdd(&p.cnt[0], 1);
    if (i1 < L1CAP) { p.l1r[i1] = tgt; p.l1w[i1] = 1.0f; }
    int old = atomicCAS(&p.slot[tgt], -1, -2);
    if (old == -1) {
      p.deg[tgt] = 1.0f;
      int idx = atomicAdd(&p.cnt[1], 1);
      if (idx < SCAP) { p.s1[idx] = tgt; p.slot[tgt] = idx; }
      else            { p.slot[tgt] = -3; }
    }
  }
  grid.sync();

  // ---------- P3: passB (edges into S1; mark rows deg-needed) ----------
  {
    int ns = p.cnt[1]; if (ns > SCAP) ns = SCAP;
    for (int j = g; j < ns; j += gs) {   // S1 self loops
      int idx = atomicAdd(&p.cnt[2], 1);
      if (idx < L2CAP) { p.l2r[idx] = p.s1[j]; p.l2s[idx] = j; p.l2w[idx] = 1.0f; }
    }
    for (long e = g; e < E; e += gs) {
      int c = p.wscol[e];
      int s = p.slot[c];
      if (s >= 0) {
        int r = is64 ? (int)ell[e] : p.ei[e];
        int idx = atomicAdd(&p.cnt[2], 1);
        if (idx < L2CAP) { p.l2r[idx] = r; p.l2s[idx] = s; p.l2w[idx] = p.ew[e]; }
        int old = atomicCAS(&p.slot[r], -1, -3);
        if (old == -1) p.deg[r] = 1.0f;
      }
    }
  }
  grid.sync();

  // ---------- P4: passC (deg for marked nodes only, ~5K atomics) ----------
  for (long e = g; e < E; e += gs) {
    int c = p.wscol[e];
    if (p.slot[c] != -1) atomicAdd(&p.deg[c], p.ew[e]);
  }
  grid.sync();

  // ---------- P5: h1[s] += norm * (x[r] @ W1), one block per l2 edge ----------
  {
    int n2 = p.cnt[2]; if (n2 > L2CAP) n2 = L2CAP;
    for (int b = blockIdx.x; b < n2; b += gridDim.x) {
      int r = p.l2r[b], s = p.l2s[b];
      float wt = p.l2w[b];
      int c = p.s1[s];
      float norm = rsqrtf(p.deg[r]) * wt * rsqrtf(p.deg[c]);
      if (tid < INDIM) shf[tid] = p.x[(long)r * INDIM + tid];
      __syncthreads();
      float acc = 0.f;
      #pragma unroll 8
      for (int k = 0; k < INDIM; ++k) acc += shf[k] * p.W1[k * HID + tid];
      atomicAdd(&p.h1[s * HID + tid], norm * acc);
      __syncthreads();
    }
  }
  grid.sync();

  // ---------- P6: h2 += norm * (relu(h1)+b1) @ W2, one block per l1 edge ----------
  {
    int n1 = p.cnt[0]; if (n1 > L1CAP) n1 = L1CAP;
    float dti = rsqrtf(p.deg[tgt]);
    for (int b = blockIdx.x; b < n1; b += gridDim.x) {
      int v = p.l1r[b]; float wt = p.l1w[b];
      int s = p.slot[v];
      shf[tid] = (s >= 0) ? fmaxf(p.h1[s * HID + tid] + p.b1[tid], 0.f) : 0.f;
      __syncthreads();
      float norm = rsqrtf(p.deg[v]) * wt * dti;
      float acc = 0.f;
      #pragma unroll 8
      for (int k = 0; k < HID; ++k) acc += shf[k] * p.W2[k * HID + tid];
      atomicAdd(&p.h2[tid], norm * acc);
      __syncthreads();
    }
  }
  grid.sync();

  // ---------- P7: MLP head on block 0 ----------
  if (blockIdx.x == 0) {
    float* feat = shf;          // 480
    float* f1   = shf + 480;    // 512
    float* f2   = shf + 992;    // 128
    feat[tid] = fmaxf(p.h2[tid] + p.b2[tid], 0.f) * p.mask[tgt];
    int wtI = p.wtI[0], mutI = p.mutI[0];  // small non-negative; low word ok i32/i64
    if (tid < 64) {
      float a = p.aa[wtI * 64 + tid];
      float b = p.aa[mutI * 64 + tid];
      feat[256 + tid] = a; feat[320 + tid] = b; feat[384 + tid] = b - a;
    }
    int pos = tgt; if (pos > 511) pos = 511; if (pos < 0) pos = 0;
    if (tid < 32) feat[448 + tid] = p.pemb[pos * 32 + tid];
    __syncthreads();
    for (int half = 0; half < 2; ++half) {
      int o = half * NTHR + tid;
      float v = p.bh1[o];
      for (int k = 0; k < 480; ++k) v += feat[k] * p.Wh1[k * 512 + o];
      f1[o] = fmaxf(v, 0.f);
    }
    __syncthreads();
    if (tid < 128) {
      float v = p.bh2[tid];
      for (int k = 0; k < 512; ++k) v += f1[k] * p.Wh2[k * 128 + tid];
      f2[tid] = fmaxf(v, 0.f) * p.Wh3[tid];
    }
    __syncthreads();
    if (tid == 0) {
      float s = p.bh3[0];
      for (int k = 0; k < 128; ++k) s += f2[k];
      p.out[0] = s;
    }
  }
}

extern "C" void kernel_launch(void* const* d_in, const int* in_sizes, int n_in,
                              void* d_out, int out_size, void* d_ws, size_t ws_size,
                              hipStream_t stream) {
  Params p;
  p.x    = (const float*)d_in[0];
  p.ei   = (const int*)d_in[1];
  p.ew   = (const float*)d_in[2];
  p.mask = (const float*)d_in[3];
  p.wtI  = (const int*)d_in[4];
  p.mutI = (const int*)d_in[5];
  p.W1   = (const float*)d_in[6];
  p.b1   = (const float*)d_in[7];
  p.W2   = (const float*)d_in[8];
  p.b2   = (const float*)d_in[9];
  p.aa   = (const float*)d_in[10];
  p.pemb = (const float*)d_in[11];
  p.Wh1  = (const float*)d_in[12];
  p.bh1  = (const float*)d_in[13];
  p.Wh2  = (const float*)d_in[14];
  p.bh2  = (const float*)d_in[15];
  p.Wh3  = (const float*)d_in[16];
  p.bh3  = (const float*)d_in[17];
  p.out  = (float*)d_out;
  p.N = in_sizes[3];   // mut_mask length
  p.E = in_sizes[2];   // edge_weight length

  char* q = (char*)d_ws;
  auto take = [&](size_t bytes) -> char* {
    char* r = q; q += (bytes + 255) & ~(size_t)255; return r;
  };
  p.cnt    = (int*)take(64);
  p.deg    = (float*)take((size_t)p.N * 4);
  p.slot   = (int*)take((size_t)p.N * 4);
  p.s1     = (int*)take(SCAP * 4);
  p.l1r    = (int*)take(L1CAP * 4);
  p.l1w    = (float*)take(L1CAP * 4);
  p.l2r    = (int*)take(L2CAP * 4);
  p.l2s    = (int*)take(L2CAP * 4);
  p.l2w    = (float*)take(L2CAP * 4);
  p.h1     = (float*)take((size_t)SCAP * HID * 4);
  p.h2     = (float*)take(HID * 4);
  p.wscol  = (int*)take((size_t)p.E * 4);
  p.blkKey = (unsigned long long*)take(NBLK * 8);

  void* args[] = { &p };
  hipLaunchCooperativeKernel((const void*)kfused, dim3(NBLK), dim3(NTHR),
                             args, 0, stream);
}

// Round 4
// 181.682 us; speedup vs baseline: 3.4126x; 3.4126x over previous
//
#include <hip/hip_runtime.h>

// Sparse 2-hop GCN slice: output depends only on h2[tgt], tgt = argmax(mut_mask).
// R4: back to multi-kernel (grid.sync costs ~65us/sync on MI355X — R3 post-mortem).
// 7 dispatches: kinit(+argmax) | passA(+int32 convert) | passB | passC | kh1 | kh2 | khead.

#define SCAP   512      // cap on |S1|; expected ~17
#define L1CAP  512      // cap on edges into tgt; expected ~17
#define L2CAP  16384    // cap on edges into S1; expected ~300
#define HID    256
#define INDIM  128

struct WsPtrs {
  int* cnt;                 // [0]=cntL1 [1]=cntS1 [2]=cntL2 [3]=is64 [4]=tgt
  float* deg;               // [N] lazily initialized
  int* slot;                // [N] -1 unknown, >=0 S1 slot, -2 transient, -3 deg-needed
  int* s1;                  // [SCAP]
  int* l1r; float* l1w;     // edges into tgt
  int* l2r; int* l2s; float* l2w; // edges into S1
  float* h1; float* h2;     // accumulators
  int* wscol;               // [E] col as int32
};

// K1: init slot/h1/h2/cnt + is64 detect + argmax (one-hot mask -> plain store)
__global__ void kinit(WsPtrs w, const int* eiraw, const float* mask, int N, int E) {
  int g = blockIdx.x * blockDim.x + threadIdx.x;
  int gs = gridDim.x * blockDim.x;
  for (int j = g; j < N; j += gs) {
    w.slot[j] = -1;
    float m = mask[j];
    if (m > 0.f) w.cnt[4] = j;       // one-hot: exactly one thread fires
  }
  for (int j = g; j < SCAP * HID; j += gs) w.h1[j] = 0.f;
  if (g < HID) w.h2[g] = 0.f;
  if (g < 3)   w.cnt[g] = 0;
  if (g == 3) {
    int is64 = 1;
    long step = E / 20; if (step < 1) step = 1;
    for (int j = 1; j <= 16; ++j) {
      long idx = (long)j * step; if (idx >= E) break;
      if (eiraw[2 * idx + 1] != 0) { is64 = 0; break; }  // ids < 2^31 -> hi word 0
    }
    w.cnt[3] = is64;
  }
}

__device__ __forceinline__ void reg_s1(WsPtrs& w, int r) {
  int old = atomicCAS(&w.slot[r], -1, -2);
  if (old == -1) {
    w.deg[r] = 1.0f;                       // lazy init, self-loop weight
    int idx = atomicAdd(&w.cnt[1], 1);
    if (idx < SCAP) { w.s1[idx] = r; w.slot[r] = idx; }
    else            { w.slot[r] = -3; }
  }
}

// K2: scan int64/int32 col; emit int32 wscol; collect edges into tgt; build S1
__global__ void kpassA(WsPtrs w, const int* eiraw, const float* ew, int E) {
  const int tgt = w.cnt[4];
  const bool is64 = w.cnt[3] != 0;
  const long long* ell = (const long long*)eiraw;
  int g = blockIdx.x * blockDim.x + threadIdx.x;
  int gs = gridDim.x * blockDim.x;
  for (long e = g; e < E; e += gs) {
    int c = is64 ? (int)ell[(long)E + e] : eiraw[(long)E + e];
    w.wscol[e] = c;
    if (c == tgt) {
      int r = is64 ? (int)ell[e] : eiraw[e];
      int i1 = atomicAdd(&w.cnt[0], 1);
      if (i1 < L1CAP) { w.l1r[i1] = r; w.l1w[i1] = ew[e]; }
      reg_s1(w, r);
    }
  }
  if (g == 0) {  // tgt's self loop (weight 1.0)
    int i1 = atomicAdd(&w.cnt[0], 1);
    if (i1 < L1CAP) { w.l1r[i1] = tgt; w.l1w[i1] = 1.0f; }
    reg_s1(w, tgt);
  }
}

// K3: scan wscol (int4); collect edges into S1; mark rows deg-needed
__global__ void kpassB(WsPtrs w, const int* eiraw, const float* ew, int E) {
  const bool is64 = w.cnt[3] != 0;
  const long long* ell = (const long long*)eiraw;
  int g = blockIdx.x * blockDim.x + threadIdx.x;
  int gs = gridDim.x * blockDim.x;
  int ns = w.cnt[1]; if (ns > SCAP) ns = SCAP;
  for (int j = g; j < ns; j += gs) {   // S1 self loops
    int idx = atomicAdd(&w.cnt[2], 1);
    if (idx < L2CAP) { w.l2r[idx] = w.s1[j]; w.l2s[idx] = j; w.l2w[idx] = 1.0f; }
  }
  const int4* c4 = (const int4*)w.wscol;
  int nv = E >> 2;
  for (int j = g; j < nv; j += gs) {
    int4 v = c4[j];
    #pragma unroll
    for (int t = 0; t < 4; ++t) {
      int c = (t == 0) ? v.x : (t == 1) ? v.y : (t == 2) ? v.z : v.w;
      int s = w.slot[c];
      if (s >= 0) {
        long e = 4L * j + t;
        int r = is64 ? (int)ell[e] : eiraw[e];
        int idx = atomicAdd(&w.cnt[2], 1);
        if (idx < L2CAP) { w.l2r[idx] = r; w.l2s[idx] = s; w.l2w[idx] = ew[e]; }
        int old = atomicCAS(&w.slot[r], -1, -3);
        if (old == -1) w.deg[r] = 1.0f;
      }
    }
  }
  for (long e = 4L * nv + g; e < E; e += gs) {
    int c = w.wscol[e];
    int s = w.slot[c];
    if (s >= 0) {
      int r = is64 ? (int)ell[e] : eiraw[e];
      int idx = atomicAdd(&w.cnt[2], 1);
      if (idx < L2CAP) { w.l2r[idx] = r; w.l2s[idx] = s; w.l2w[idx] = ew[e]; }
      int old = atomicCAS(&w.slot[r], -1, -3);
      if (old == -1) w.deg[r] = 1.0f;
    }
  }
}

// K4: deg accumulation for marked nodes only (~5K atomics)
__global__ void kpassC(WsPtrs w, const float* ew, int E) {
  int g = blockIdx.x * blockDim.x + threadIdx.x;
  int gs = gridDim.x * blockDim.x;
  const int4* c4 = (const int4*)w.wscol;
  int nv = E >> 2;
  for (int j = g; j < nv; j += gs) {
    int4 v = c4[j];
    #pragma unroll
    for (int t = 0; t < 4; ++t) {
      int c = (t == 0) ? v.x : (t == 1) ? v.y : (t == 2) ? v.z : v.w;
      if (w.slot[c] != -1) atomicAdd(&w.deg[c], ew[4L * j + t]);
    }
  }
  for (long e = 4L * nv + g; e < E; e += gs) {
    int c = w.wscol[e];
    if (w.slot[c] != -1) atomicAdd(&w.deg[c], ew[e]);
  }
}

// K5: one block per l2 edge: h1[s] += norm * (x[r] @ W1)
__global__ void kh1(WsPtrs w, const float* x, const float* W1) {
  __shared__ float xs[INDIM];
  int n = w.cnt[2]; if (n > L2CAP) n = L2CAP;
  int tid = threadIdx.x;
  for (int b = blockIdx.x; b < n; b += gridDim.x) {
    int r = w.l2r[b], s = w.l2s[b];
    float wt = w.l2w[b];
    int c = w.s1[s];
    float norm = rsqrtf(w.deg[r]) * wt * rsqrtf(w.deg[c]);
    if (tid < INDIM) xs[tid] = x[(long)r * INDIM + tid];
    __syncthreads();
    float acc = 0.f;
    #pragma unroll 8
    for (int k = 0; k < INDIM; ++k) acc += xs[k] * W1[k * HID + tid];
    atomicAdd(&w.h1[s * HID + tid], norm * acc);
    __syncthreads();
  }
}

// K6: one block per l1 edge: h2 += norm * (relu(h1[slot[v]]+b1) @ W2)
__global__ void kh2(WsPtrs w, const float* W2, const float* b1) {
  __shared__ float hs[HID];
  int n = w.cnt[0]; if (n > L1CAP) n = L1CAP;
  int tid = threadIdx.x;
  int tgt = w.cnt[4];
  float dti = rsqrtf(w.deg[tgt]);
  for (int b = blockIdx.x; b < n; b += gridDim.x) {
    int v = w.l1r[b]; float wt = w.l1w[b];
    int s = w.slot[v];
    hs[tid] = (s >= 0) ? fmaxf(w.h1[s * HID + tid] + b1[tid], 0.f) : 0.f;
    __syncthreads();
    float norm = rsqrtf(w.deg[v]) * wt * dti;
    float acc = 0.f;
    #pragma unroll 8
    for (int k = 0; k < HID; ++k) acc += hs[k] * W2[k * HID + tid];
    atomicAdd(&w.h2[tid], norm * acc);
    __syncthreads();
  }
}

// K7: single block, 1024 threads, split-K MLP head
__global__ void __launch_bounds__(1024) khead(
    WsPtrs w, const float* b2, const float* mask,
    const int* wtI_, const int* mutI_,
    const float* aa, const float* pemb,
    const float* Wh1, const float* bh1,
    const float* Wh2, const float* bh2,
    const float* Wh3, const float* bh3,
    float* out) {
  __shared__ float feat[480];
  __shared__ float f1[512];
  __shared__ float pp[1024];
  __shared__ float f2[128];
  int t = threadIdx.x;
  int tgt = w.cnt[4];
  if (t < HID) feat[t] = fmaxf(w.h2[t] + b2[t], 0.f) * mask[tgt];
  int wtI = wtI_[0], mutI = mutI_[0];   // small non-negative; low word ok i32/i64
  if (t < 64) {
    float a = aa[wtI * 64 + t];
    float b = aa[mutI * 64 + t];
    feat[256 + t] = a; feat[320 + t] = b; feat[384 + t] = b - a;
  }
  int pos = tgt; if (pos > 511) pos = 511; if (pos < 0) pos = 0;
  if (t < 32) feat[448 + t] = pemb[pos * 32 + t];
  __syncthreads();
  // layer 1: 512 outputs, K=480 split in 2
  {
    int o = t & 511, half = t >> 9;
    int k0 = half * 240, k1 = k0 + 240;
    float v = 0.f;
    for (int k = k0; k < k1; ++k) v += feat[k] * Wh1[k * 512 + o];
    pp[t] = v;
  }
  __syncthreads();
  if (t < 512) f1[t] = fmaxf(pp[t] + pp[t + 512] + bh1[t], 0.f);
  __syncthreads();
  // layer 2: 128 outputs, K=512 split in 8
  {
    int o = t & 127, part = t >> 7;
    int k0 = part * 64, k1 = k0 + 64;
    float v = 0.f;
    for (int k = k0; k < k1; ++k) v += f1[k] * Wh2[k * 128 + o];
    pp[t] = v;
  }
  __syncthreads();
  if (t < 128) {
    float v = bh2[t];
    #pragma unroll
    for (int j = 0; j < 8; ++j) v += pp[j * 128 + t];
    f2[t] = fmaxf(v, 0.f) * Wh3[t];
  }
  __syncthreads();
  if (t == 0) {
    float s = bh3[0];
    for (int k = 0; k < 128; ++k) s += f2[k];
    out[0] = s;
  }
}

extern "C" void kernel_launch(void* const* d_in, const int* in_sizes, int n_in,
                              void* d_out, int out_size, void* d_ws, size_t ws_size,
                              hipStream_t stream) {
  const float* x    = (const float*)d_in[0];
  const int*   ei   = (const int*)d_in[1];
  const float* ew   = (const float*)d_in[2];
  const float* mask = (const float*)d_in[3];
  const int*   wtI  = (const int*)d_in[4];
  const int*   mutI = (const int*)d_in[5];
  const float* W1   = (const float*)d_in[6];
  const float* b1   = (const float*)d_in[7];
  const float* W2   = (const float*)d_in[8];
  const float* b2   = (const float*)d_in[9];
  const float* aa   = (const float*)d_in[10];
  const float* pemb = (const float*)d_in[11];
  const float* Wh1  = (const float*)d_in[12];
  const float* bh1  = (const float*)d_in[13];
  const float* Wh2  = (const float*)d_in[14];
  const float* bh2  = (const float*)d_in[15];
  const float* Wh3  = (const float*)d_in[16];
  const float* bh3  = (const float*)d_in[17];
  float* out = (float*)d_out;
  const int N = in_sizes[3];   // mut_mask length
  const int E = in_sizes[2];   // edge_weight length

  char* q = (char*)d_ws;
  auto take = [&](size_t bytes) -> char* {
    char* r = q; q += (bytes + 255) & ~(size_t)255; return r;
  };
  WsPtrs w;
  w.cnt   = (int*)take(64);
  w.deg   = (float*)take((size_t)N * 4);
  w.slot  = (int*)take((size_t)N * 4);
  w.s1    = (int*)take(SCAP * 4);
  w.l1r   = (int*)take(L1CAP * 4);
  w.l1w   = (float*)take(L1CAP * 4);
  w.l2r   = (int*)take(L2CAP * 4);
  w.l2s   = (int*)take(L2CAP * 4);
  w.l2w   = (float*)take(L2CAP * 4);
  w.h1    = (float*)take((size_t)SCAP * HID * 4);
  w.h2    = (float*)take(HID * 4);
  w.wscol = (int*)take((size_t)E * 4);

  kinit  <<<512, 256, 0, stream>>>(w, ei, mask, N, E);
  kpassA <<<2048, 256, 0, stream>>>(w, ei, ew, E);
  kpassB <<<1024, 256, 0, stream>>>(w, ei, ew, E);
  kpassC <<<1024, 256, 0, stream>>>(w, ew, E);
  kh1    <<<512, 256, 0, stream>>>(w, x, W1);
  kh2    <<<64, 256, 0, stream>>>(w, W2, b1);
  khead  <<<1, 1024, 0, stream>>>(w, b2, mask, wtI, mutI, aa, pemb,
                                  Wh1, bh1, Wh2, bh2, Wh3, bh3, out);
}